// Round 3
// baseline (439.970 us; speedup 1.0000x reference)
//
#include <hip/hip_runtime.h>
#include <hip/hip_bf16.h>
#include <stdint.h>
#include <string.h>

typedef __bf16 bf16x8 __attribute__((ext_vector_type(8)));
typedef float  f32x4  __attribute__((ext_vector_type(4)));

// Convert 8 consecutive fp32 (two float4s) to packed bf16x8 (RNE).
static __device__ inline bf16x8 cvt8(const float4 a, const float4 b) {
    bf16x8 r;
    r[0] = (__bf16)a.x; r[1] = (__bf16)a.y; r[2] = (__bf16)a.z; r[3] = (__bf16)a.w;
    r[4] = (__bf16)b.x; r[5] = (__bf16)b.y; r[6] = (__bf16)b.z; r[7] = (__bf16)b.w;
    return r;
}

// ---------------- pre-pass: fp32 -> bf16 tables in workspace ----------------
// Streams z_user (6.4M), z_books (6.4M), W1 (8K) once; writes packed bf16.
// ~77 MB of HBM traffic ≈ 13 us.
__global__ __launch_bounds__(256)
void cvt_bf16_pass(const float* __restrict__ zu, const float* __restrict__ zb,
                   const float* __restrict__ w1,
                   uint4* __restrict__ zub, uint4* __restrict__ zbb,
                   uint4* __restrict__ w1b,
                   const int ngu, const int ngb, const int ngw) // groups of 8 floats
{
    const int stride = gridDim.x * blockDim.x;
    const int tid = blockIdx.x * blockDim.x + threadIdx.x;
    for (int i = tid; i < ngu; i += stride) {
        const float4* s = (const float4*)zu + 2 * (size_t)i;
        zub[i] = __builtin_bit_cast(uint4, cvt8(s[0], s[1]));
    }
    for (int i = tid; i < ngb; i += stride) {
        const float4* s = (const float4*)zb + 2 * (size_t)i;
        zbb[i] = __builtin_bit_cast(uint4, cvt8(s[0], s[1]));
    }
    for (int i = tid; i < ngw; i += stride) {
        const float4* s = (const float4*)w1 + 2 * (size_t)i;
        w1b[i] = __builtin_bit_cast(uint4, cvt8(s[0], s[1]));
    }
}

// ---------------- main kernel: bf16 gather + MFMA ----------------
// One wave per 16 edges: A = concat(zu[row], zb[col]) [16x128] bf16 (gathered),
// B = W1^T as 4 N-tiles x 4 K-steps of mfma_f32_16x16x32_bf16, fp32 epilogue
// h=relu(.+b1) then per-edge dot with W2 via quad-local shfl reduction.
// Layouts (measured): A: lane=(m,quad) holds A[m][k=quad*8+j];
// B: lane holds B[k=quad*8+j][n=m]; C/D: reg r = D[row=quad*4+r][col=m].
__global__ __launch_bounds__(256, 8)
void edge_decoder_mfma_bf16(const uint4* __restrict__ zub,   // [100k][8] 16B chunks
                            const uint4* __restrict__ zbb,
                            const int*   __restrict__ eidx,
                            const uint4* __restrict__ w1b,   // [64 rows][16 chunks]
                            const float* __restrict__ b1,
                            const float* __restrict__ w2,
                            const float* __restrict__ b2,
                            float*       __restrict__ out,
                            const int nedges)
{
    const int lane = threadIdx.x & 63;
    const int m    = lane & 15;
    const int quad = lane >> 4;

    const int wavesPerBlock = blockDim.x >> 6;
    const int gwave  = blockIdx.x * wavesPerBlock + (threadIdx.x >> 6);
    const int nwaves = gridDim.x * wavesPerBlock;

    // W1 B-fragments: Bf[t][s] = 16B at row n=t*16+m, k-chunk s*4+quad.
    // (W1 is 16 KB bf16, L1-resident; compiler may re-load in-loop at 64-VGPR
    // budget — those are L1 hits.)
    bf16x8 Bf[4][4];
#pragma unroll
    for (int t = 0; t < 4; ++t)
#pragma unroll
        for (int s = 0; s < 4; ++s)
            Bf[t][s] = __builtin_bit_cast(bf16x8, w1b[(t * 16 + m) * 16 + s * 4 + quad]);

    float w2v[4], b1v[4];
#pragma unroll
    for (int t = 0; t < 4; ++t) {
        w2v[t] = w2[t * 16 + m];
        b1v[t] = b1[t * 16 + m];
    }
    const float b2f = b2[0];

    const int* __restrict__ rowp = eidx;
    const int* __restrict__ colp = eidx + nedges;
    const int ngroups = (nedges + 15) >> 4;

    for (int g = gwave; g < ngroups; g += nwaves) {
        const int ebase = g << 4;
        int e = ebase + m;
        if (e >= nedges) e = nedges - 1;          // tail clamp (stores masked below)
        const int r = rowp[e];
        const int c = colp[e];

        // Row = 64 bf16 = 8 x 16B chunks. Lane (m,quad): chunks {quad, quad+4}
        // of user row and book row -> 4 gather loads/lane (was 8 in fp32).
        const uint4* up = zub + (size_t)r * 8;
        const uint4* vp = zbb + (size_t)c * 8;
        bf16x8 A0 = __builtin_bit_cast(bf16x8, up[quad]);      // k [0,32)
        bf16x8 A1 = __builtin_bit_cast(bf16x8, up[quad + 4]);  // k [32,64)
        bf16x8 A2 = __builtin_bit_cast(bf16x8, vp[quad]);      // k [64,96)
        bf16x8 A3 = __builtin_bit_cast(bf16x8, vp[quad + 4]);  // k [96,128)

        f32x4 acc[4];
#pragma unroll
        for (int t = 0; t < 4; ++t) acc[t] = (f32x4){0.f, 0.f, 0.f, 0.f};

#pragma unroll
        for (int t = 0; t < 4; ++t) {
            acc[t] = __builtin_amdgcn_mfma_f32_16x16x32_bf16(A0, Bf[t][0], acc[t], 0, 0, 0);
            acc[t] = __builtin_amdgcn_mfma_f32_16x16x32_bf16(A1, Bf[t][1], acc[t], 0, 0, 0);
            acc[t] = __builtin_amdgcn_mfma_f32_16x16x32_bf16(A2, Bf[t][2], acc[t], 0, 0, 0);
            acc[t] = __builtin_amdgcn_mfma_f32_16x16x32_bf16(A3, Bf[t][3], acc[t], 0, 0, 0);
        }

        // fp32 epilogue: relu + dot(W2) partials, reduce 16 n-lanes per quad.
        float p[4] = {0.f, 0.f, 0.f, 0.f};
#pragma unroll
        for (int t = 0; t < 4; ++t) {
#pragma unroll
            for (int rr = 0; rr < 4; ++rr) {
                float h = fmaxf(acc[t][rr] + b1v[t], 0.f);
                p[rr] = fmaf(h, w2v[t], p[rr]);
            }
        }
#pragma unroll
        for (int off = 8; off >= 1; off >>= 1)
#pragma unroll
            for (int rr = 0; rr < 4; ++rr)
                p[rr] += __shfl_xor(p[rr], off, 64);

        if (m == 0) {
            const int eo = ebase + quad * 4;
            if (eo + 3 < nedges) {
                float4 o;
                o.x = p[0] + b2f; o.y = p[1] + b2f;
                o.z = p[2] + b2f; o.w = p[3] + b2f;
                *(float4*)(out + eo) = o;
            } else {
#pragma unroll
                for (int rr = 0; rr < 4; ++rr)
                    if (eo + rr < nedges) out[eo + rr] = p[rr] + b2f;
            }
        }
    }
}

// ---------------- fallback: fp32 gather (no workspace needed) ----------------
__global__ __launch_bounds__(256, 4)
void edge_decoder_mfma_f32(const float* __restrict__ zu,
                           const float* __restrict__ zb,
                           const int*   __restrict__ eidx,
                           const float* __restrict__ w1,
                           const float* __restrict__ b1,
                           const float* __restrict__ w2,
                           const float* __restrict__ b2,
                           float*       __restrict__ out,
                           const int nedges)
{
    const int lane = threadIdx.x & 63;
    const int m    = lane & 15;
    const int quad = lane >> 4;
    const int wavesPerBlock = blockDim.x >> 6;
    const int gwave  = blockIdx.x * wavesPerBlock + (threadIdx.x >> 6);
    const int nwaves = gridDim.x * wavesPerBlock;

    bf16x8 Bf[4][4];
#pragma unroll
    for (int t = 0; t < 4; ++t) {
        const float4* wrow = (const float4*)(w1 + (size_t)(t * 16 + m) * 128);
#pragma unroll
        for (int s = 0; s < 4; ++s) {
            const int c0 = s * 8 + quad * 2;
            Bf[t][s] = cvt8(wrow[c0], wrow[c0 + 1]);
        }
    }
    float w2v[4], b1v[4];
#pragma unroll
    for (int t = 0; t < 4; ++t) {
        w2v[t] = w2[t * 16 + m];
        b1v[t] = b1[t * 16 + m];
    }
    const float b2f = b2[0];
    const int* __restrict__ rowp = eidx;
    const int* __restrict__ colp = eidx + nedges;
    const int ngroups = (nedges + 15) >> 4;

    for (int g = gwave; g < ngroups; g += nwaves) {
        const int ebase = g << 4;
        int e = ebase + m;
        if (e >= nedges) e = nedges - 1;
        const int r = rowp[e];
        const int c = colp[e];
        const float4* up = (const float4*)(zu + (size_t)r * 64);
        const float4* vp = (const float4*)(zb + (size_t)c * 64);
        bf16x8 A0 = cvt8(up[quad * 2],     up[quad * 2 + 1]);
        bf16x8 A1 = cvt8(up[8 + quad * 2], up[9 + quad * 2]);
        bf16x8 A2 = cvt8(vp[quad * 2],     vp[quad * 2 + 1]);
        bf16x8 A3 = cvt8(vp[8 + quad * 2], vp[9 + quad * 2]);

        f32x4 acc[4];
#pragma unroll
        for (int t = 0; t < 4; ++t) acc[t] = (f32x4){0.f, 0.f, 0.f, 0.f};
#pragma unroll
        for (int t = 0; t < 4; ++t) {
            acc[t] = __builtin_amdgcn_mfma_f32_16x16x32_bf16(A0, Bf[t][0], acc[t], 0, 0, 0);
            acc[t] = __builtin_amdgcn_mfma_f32_16x16x32_bf16(A1, Bf[t][1], acc[t], 0, 0, 0);
            acc[t] = __builtin_amdgcn_mfma_f32_16x16x32_bf16(A2, Bf[t][2], acc[t], 0, 0, 0);
            acc[t] = __builtin_amdgcn_mfma_f32_16x16x32_bf16(A3, Bf[t][3], acc[t], 0, 0, 0);
        }
        float p[4] = {0.f, 0.f, 0.f, 0.f};
#pragma unroll
        for (int t = 0; t < 4; ++t)
#pragma unroll
            for (int rr = 0; rr < 4; ++rr) {
                float h = fmaxf(acc[t][rr] + b1v[t], 0.f);
                p[rr] = fmaf(h, w2v[t], p[rr]);
            }
#pragma unroll
        for (int off = 8; off >= 1; off >>= 1)
#pragma unroll
            for (int rr = 0; rr < 4; ++rr)
                p[rr] += __shfl_xor(p[rr], off, 64);

        if (m == 0) {
            const int eo = ebase + quad * 4;
            if (eo + 3 < nedges) {
                float4 o;
                o.x = p[0] + b2f; o.y = p[1] + b2f;
                o.z = p[2] + b2f; o.w = p[3] + b2f;
                *(float4*)(out + eo) = o;
            } else {
#pragma unroll
                for (int rr = 0; rr < 4; ++rr)
                    if (eo + rr < nedges) out[eo + rr] = p[rr] + b2f;
            }
        }
    }
}

extern "C" void kernel_launch(void* const* d_in, const int* in_sizes, int n_in,
                              void* d_out, int out_size, void* d_ws, size_t ws_size,
                              hipStream_t stream) {
    const float* zu = (const float*)d_in[0];
    const float* zb = (const float*)d_in[1];
    const int*   ei = (const int*)d_in[2];
    const float* w1 = (const float*)d_in[3];
    const float* b1 = (const float*)d_in[4];
    const float* w2 = (const float*)d_in[5];
    const float* b2 = (const float*)d_in[6];
    float* out = (float*)d_out;

    const int nedges = in_sizes[2] / 2;     // edge_label_index is [2, E]
    const int nzu = in_sizes[0];            // z_user floats
    const int nzb = in_sizes[1];            // z_books floats
    const int nw1 = in_sizes[3];            // W1 floats (64*128)

    // Workspace layout: zub | zbb | w1b, all packed bf16 (2 B/elem).
    const size_t zub_bytes = (size_t)nzu * 2;
    const size_t zbb_bytes = (size_t)nzb * 2;
    const size_t w1b_bytes = (size_t)nw1 * 2;
    const size_t need = zub_bytes + zbb_bytes + w1b_bytes;

    // grid 2048 x 256 = 8192 waves = 100% residency at 8 waves/SIMD (VGPR<=64).
    dim3 block(256);

    if (ws_size >= need) {
        uint4* zub = (uint4*)d_ws;
        uint4* zbb = (uint4*)((char*)d_ws + zub_bytes);
        uint4* w1b = (uint4*)((char*)d_ws + zub_bytes + zbb_bytes);
        hipLaunchKernelGGL(cvt_bf16_pass, dim3(2048), block, 0, stream,
                           zu, zb, w1, zub, zbb, w1b,
                           nzu / 8, nzb / 8, nw1 / 8);
        hipLaunchKernelGGL(edge_decoder_mfma_bf16, dim3(2048), block, 0, stream,
                           zub, zbb, ei, w1b, b1, w2, b2, out, nedges);
    } else {
        hipLaunchKernelGGL(edge_decoder_mfma_f32, dim3(2048), block, 0, stream,
                           zu, zb, ei, w1, b1, w2, b2, out, nedges);
    }
}

// Round 4
// 359.692 us; speedup vs baseline: 1.2232x; 1.2232x over previous
//
#include <hip/hip_runtime.h>
#include <hip/hip_bf16.h>
#include <stdint.h>
#include <string.h>

typedef __bf16 bf16x8 __attribute__((ext_vector_type(8)));
typedef float  f32x4  __attribute__((ext_vector_type(4)));

// Convert 8 consecutive fp32 (two float4s) to packed bf16x8 (RNE).
static __device__ inline bf16x8 cvt8(const float4 a, const float4 b) {
    bf16x8 r;
    r[0] = (__bf16)a.x; r[1] = (__bf16)a.y; r[2] = (__bf16)a.z; r[3] = (__bf16)a.w;
    r[4] = (__bf16)b.x; r[5] = (__bf16)b.y; r[6] = (__bf16)b.z; r[7] = (__bf16)b.w;
    return r;
}

// ---------------- pre-pass: fp32 -> bf16 in workspace ----------------
// Tables packed row-major bf16; W1 packed in MFMA B-FRAGMENT order:
//   w1frag[(t*4+s)*64 + lane] = 16B = bf16{ W1[n=t*16+(lane&15)]
//                                             [k=s*32+(lane>>4)*8 + j] , j=0..7 }
// so the main kernel's LDS read for MFMA(t,s) is lane-contiguous (conflict-free).
__global__ __launch_bounds__(256)
void cvt_bf16_pass(const float* __restrict__ zu, const float* __restrict__ zb,
                   const float* __restrict__ w1,
                   uint4* __restrict__ zub, uint4* __restrict__ zbb,
                   uint4* __restrict__ w1f,
                   const int ngu, const int ngb)   // groups of 8 floats
{
    const int stride = gridDim.x * blockDim.x;
    const int tid = blockIdx.x * blockDim.x + threadIdx.x;
    for (int i = tid; i < ngu; i += stride) {
        const float4* s = (const float4*)zu + 2 * (size_t)i;
        zub[i] = __builtin_bit_cast(uint4, cvt8(s[0], s[1]));
    }
    for (int i = tid; i < ngb; i += stride) {
        const float4* s = (const float4*)zb + 2 * (size_t)i;
        zbb[i] = __builtin_bit_cast(uint4, cvt8(s[0], s[1]));
    }
    if (tid < 1024) {                       // 16 fragments x 64 lanes
        const int fid  = tid >> 6, lane = tid & 63;
        const int t = fid >> 2, s = fid & 3;
        const int n  = t * 16 + (lane & 15);
        const int k0 = s * 32 + (lane >> 4) * 8;
        const float4* src = (const float4*)(w1 + (size_t)n * 128 + k0);
        w1f[tid] = __builtin_bit_cast(uint4, cvt8(src[0], src[1]));
    }
}

// ---------------- main kernel: bf16 gather + MFMA, W1 in LDS ----------------
// One wave per 16 edges: A = concat(zu[row], zb[col]) [16x128] bf16 gathered;
// B = W1^T as 4 N-tiles x 4 K-steps of mfma_f32_16x16x32_bf16 with B-fragments
// ds_read from LDS per-MFMA (keeps VGPRs ~70; NO loop-invariant 64-reg array —
// R3 showed launch_bounds-forced spill of it costs 2x in HBM scratch traffic).
// fp32 epilogue: h=relu(.+b1), dot W2, quad-local shfl reduce, packed store.
__global__ __launch_bounds__(256, 6)
void edge_decoder_mfma_bf16(const uint4* __restrict__ zub,   // [100k][8] 16B chunks
                            const uint4* __restrict__ zbb,
                            const int*   __restrict__ eidx,
                            const uint4* __restrict__ w1f,   // [16][64] fragments
                            const float* __restrict__ b1,
                            const float* __restrict__ w2,
                            const float* __restrict__ b2,
                            float*       __restrict__ out,
                            const int nedges)
{
    __shared__ uint4 w1lds[16 * 64];        // 16 KB

    const int lane = threadIdx.x & 63;
    const int m    = lane & 15;
    const int quad = lane >> 4;

    // Block-cooperative LDS fill: 256 threads x 4 sweeps, coalesced.
#pragma unroll
    for (int i = 0; i < 4; ++i)
        w1lds[i * 256 + threadIdx.x] = w1f[i * 256 + threadIdx.x];
    __syncthreads();

    float w2v[4], b1v[4];
#pragma unroll
    for (int t = 0; t < 4; ++t) {
        w2v[t] = w2[t * 16 + m];
        b1v[t] = b1[t * 16 + m];
    }
    const float b2f = b2[0];

    const int wavesPerBlock = blockDim.x >> 6;
    const int gwave  = blockIdx.x * wavesPerBlock + (threadIdx.x >> 6);
    const int nwaves = gridDim.x * wavesPerBlock;

    const int* __restrict__ rowp = eidx;
    const int* __restrict__ colp = eidx + nedges;
    const int ngroups = (nedges + 15) >> 4;

    const uint4* lfrag = w1lds + lane;      // lane-contiguous fragment base

    for (int g = gwave; g < ngroups; g += nwaves) {
        const int ebase = g << 4;
        int e = ebase + m;
        if (e >= nedges) e = nedges - 1;    // tail clamp (stores masked below)
        const int r = rowp[e];
        const int c = colp[e];

        // Gather: row = 8 x 16B chunks; lane (m,quad) takes chunks {quad,quad+4}
        // of the user row and the book row (full 128B line consumed per row).
        const uint4* up = zub + (size_t)r * 8;
        const uint4* vp = zbb + (size_t)c * 8;
        bf16x8 A[4];
        A[0] = __builtin_bit_cast(bf16x8, up[quad]);      // k [0,32)
        A[1] = __builtin_bit_cast(bf16x8, up[quad + 4]);  // k [32,64)
        A[2] = __builtin_bit_cast(bf16x8, vp[quad]);      // k [64,96)
        A[3] = __builtin_bit_cast(bf16x8, vp[quad + 4]);  // k [96,128)

        f32x4 acc[4];
#pragma unroll
        for (int t = 0; t < 4; ++t) acc[t] = (f32x4){0.f, 0.f, 0.f, 0.f};

#pragma unroll
        for (int t = 0; t < 4; ++t)
#pragma unroll
            for (int s = 0; s < 4; ++s) {
                bf16x8 B = __builtin_bit_cast(bf16x8, lfrag[(t * 4 + s) * 64]);
                acc[t] = __builtin_amdgcn_mfma_f32_16x16x32_bf16(A[s], B, acc[t], 0, 0, 0);
            }

        // fp32 epilogue: relu + dot(W2) partials, reduce the 16 n-lanes per quad.
        float p[4] = {0.f, 0.f, 0.f, 0.f};
#pragma unroll
        for (int t = 0; t < 4; ++t)
#pragma unroll
            for (int rr = 0; rr < 4; ++rr) {
                float h = fmaxf(acc[t][rr] + b1v[t], 0.f);
                p[rr] = fmaf(h, w2v[t], p[rr]);
            }
#pragma unroll
        for (int off = 8; off >= 1; off >>= 1)
#pragma unroll
            for (int rr = 0; rr < 4; ++rr)
                p[rr] += __shfl_xor(p[rr], off, 64);

        if (m == 0) {
            const int eo = ebase + quad * 4;
            if (eo + 3 < nedges) {
                float4 o;
                o.x = p[0] + b2f; o.y = p[1] + b2f;
                o.z = p[2] + b2f; o.w = p[3] + b2f;
                *(float4*)(out + eo) = o;
            } else {
#pragma unroll
                for (int rr = 0; rr < 4; ++rr)
                    if (eo + rr < nedges) out[eo + rr] = p[rr] + b2f;
            }
        }
    }
}

// ---------------- fallback: fp32 gather (no workspace needed) ----------------
__global__ __launch_bounds__(256, 4)
void edge_decoder_mfma_f32(const float* __restrict__ zu,
                           const float* __restrict__ zb,
                           const int*   __restrict__ eidx,
                           const float* __restrict__ w1,
                           const float* __restrict__ b1,
                           const float* __restrict__ w2,
                           const float* __restrict__ b2,
                           float*       __restrict__ out,
                           const int nedges)
{
    const int lane = threadIdx.x & 63;
    const int m    = lane & 15;
    const int quad = lane >> 4;
    const int wavesPerBlock = blockDim.x >> 6;
    const int gwave  = blockIdx.x * wavesPerBlock + (threadIdx.x >> 6);
    const int nwaves = gridDim.x * wavesPerBlock;

    bf16x8 Bf[4][4];
#pragma unroll
    for (int t = 0; t < 4; ++t) {
        const float4* wrow = (const float4*)(w1 + (size_t)(t * 16 + m) * 128);
#pragma unroll
        for (int s = 0; s < 4; ++s) {
            const int c0 = s * 8 + quad * 2;
            Bf[t][s] = cvt8(wrow[c0], wrow[c0 + 1]);
        }
    }
    float w2v[4], b1v[4];
#pragma unroll
    for (int t = 0; t < 4; ++t) {
        w2v[t] = w2[t * 16 + m];
        b1v[t] = b1[t * 16 + m];
    }
    const float b2f = b2[0];
    const int* __restrict__ rowp = eidx;
    const int* __restrict__ colp = eidx + nedges;
    const int ngroups = (nedges + 15) >> 4;

    for (int g = gwave; g < ngroups; g += nwaves) {
        const int ebase = g << 4;
        int e = ebase + m;
        if (e >= nedges) e = nedges - 1;
        const int r = rowp[e];
        const int c = colp[e];
        const float4* up = (const float4*)(zu + (size_t)r * 64);
        const float4* vp = (const float4*)(zb + (size_t)c * 64);
        bf16x8 A0 = cvt8(up[quad * 2],     up[quad * 2 + 1]);
        bf16x8 A1 = cvt8(up[8 + quad * 2], up[9 + quad * 2]);
        bf16x8 A2 = cvt8(vp[quad * 2],     vp[quad * 2 + 1]);
        bf16x8 A3 = cvt8(vp[8 + quad * 2], vp[9 + quad * 2]);

        f32x4 acc[4];
#pragma unroll
        for (int t = 0; t < 4; ++t) acc[t] = (f32x4){0.f, 0.f, 0.f, 0.f};
#pragma unroll
        for (int t = 0; t < 4; ++t) {
            acc[t] = __builtin_amdgcn_mfma_f32_16x16x32_bf16(A0, Bf[t][0], acc[t], 0, 0, 0);
            acc[t] = __builtin_amdgcn_mfma_f32_16x16x32_bf16(A1, Bf[t][1], acc[t], 0, 0, 0);
            acc[t] = __builtin_amdgcn_mfma_f32_16x16x32_bf16(A2, Bf[t][2], acc[t], 0, 0, 0);
            acc[t] = __builtin_amdgcn_mfma_f32_16x16x32_bf16(A3, Bf[t][3], acc[t], 0, 0, 0);
        }
        float p[4] = {0.f, 0.f, 0.f, 0.f};
#pragma unroll
        for (int t = 0; t < 4; ++t)
#pragma unroll
            for (int rr = 0; rr < 4; ++rr) {
                float h = fmaxf(acc[t][rr] + b1v[t], 0.f);
                p[rr] = fmaf(h, w2v[t], p[rr]);
            }
#pragma unroll
        for (int off = 8; off >= 1; off >>= 1)
#pragma unroll
            for (int rr = 0; rr < 4; ++rr)
                p[rr] += __shfl_xor(p[rr], off, 64);

        if (m == 0) {
            const int eo = ebase + quad * 4;
            if (eo + 3 < nedges) {
                float4 o;
                o.x = p[0] + b2f; o.y = p[1] + b2f;
                o.z = p[2] + b2f; o.w = p[3] + b2f;
                *(float4*)(out + eo) = o;
            } else {
#pragma unroll
                for (int rr = 0; rr < 4; ++rr)
                    if (eo + rr < nedges) out[eo + rr] = p[rr] + b2f;
            }
        }
    }
}

extern "C" void kernel_launch(void* const* d_in, const int* in_sizes, int n_in,
                              void* d_out, int out_size, void* d_ws, size_t ws_size,
                              hipStream_t stream) {
    const float* zu = (const float*)d_in[0];
    const float* zb = (const float*)d_in[1];
    const int*   ei = (const int*)d_in[2];
    const float* w1 = (const float*)d_in[3];
    const float* b1 = (const float*)d_in[4];
    const float* w2 = (const float*)d_in[5];
    const float* b2 = (const float*)d_in[6];
    float* out = (float*)d_out;

    const int nedges = in_sizes[2] / 2;     // edge_label_index is [2, E]
    const int nzu = in_sizes[0];            // z_user floats
    const int nzb = in_sizes[1];            // z_books floats

    // Workspace: zub | zbb | w1frag (all packed bf16, 2 B/elem; w1frag = 16 KB).
    const size_t zub_bytes = (size_t)nzu * 2;
    const size_t zbb_bytes = (size_t)nzb * 2;
    const size_t w1f_bytes = 16 * 64 * 16;
    const size_t need = zub_bytes + zbb_bytes + w1f_bytes;

    dim3 block(256);

    if (ws_size >= need) {
        uint4* zub = (uint4*)d_ws;
        uint4* zbb = (uint4*)((char*)d_ws + zub_bytes);
        uint4* w1f = (uint4*)((char*)d_ws + zub_bytes + zbb_bytes);
        hipLaunchKernelGGL(cvt_bf16_pass, dim3(2048), block, 0, stream,
                           zu, zb, w1, zub, zbb, w1f, nzu / 8, nzb / 8);
        // 1536 blocks = 6 blocks/CU at launch_bounds(256,6); grid-stride loop
        // keeps correctness at any residency.
        hipLaunchKernelGGL(edge_decoder_mfma_bf16, dim3(1536), block, 0, stream,
                           zub, zbb, ei, w1f, b1, w2, b2, out, nedges);
    } else {
        hipLaunchKernelGGL(edge_decoder_mfma_f32, dim3(2048), block, 0, stream,
                           zu, zb, ei, w1, b1, w2, b2, out, nedges);
    }
}